// Round 3
// baseline (137.916 us; speedup 1.0000x reference)
//
#include <hip/hip_runtime.h>

#define NB 2
#define NH 8
#define NS 2048
#define ND 64
#define QBLK 64
#define KBLK 64
#define NKT (NS / KBLK)     // 32
#define HKT (NKT / 2)       // 16 tiles per wave-group
#define LDST 72             // Q/K/P LDS row stride (f16)
#define VST  64             // VT row stride (f16), chunk-XOR swizzled
#define OST  68             // Osum row stride (f32)

typedef _Float16 f16x4 __attribute__((ext_vector_type(4)));
typedef _Float16 f16x8 __attribute__((ext_vector_type(8)));
typedef float    f32x4 __attribute__((ext_vector_type(4)));

#define MFMA16(A,B,C) __builtin_amdgcn_mfma_f32_16x16x32_f16((A),(B),(C),0,0,0)

__global__ __launch_bounds__(512, 4)
void sdpa_kernel(const float* __restrict__ Qg, const float* __restrict__ Kg,
                 const float* __restrict__ Vg, float* __restrict__ Og,
                 float* __restrict__ Ag)
{
    const int tid  = threadIdx.x;
    const int w    = tid >> 6;
    const int lane = tid & 63;
    const int g    = w >> 2;     // kt-group 0/1
    const int wi   = w & 3;      // wave within group
    const int lg   = lane >> 4;
    const int lc   = lane & 15;
    const int qt   = blockIdx.x;
    const int bh   = blockIdx.y;

    const size_t base = (size_t)bh * NS * ND;
    const float* Qp = Qg + base + (size_t)qt * QBLK * ND;
    const float* Kp = Kg + base;
    const float* Vp = Vg + base;
    float*       Op = Og + base + (size_t)qt * QBLK * ND;
    float*       Ap = Ag + (size_t)bh * NS * NS + (size_t)qt * QBLK * NS;

    // LDS pool: Qs[9216] | Ks[2][9216] | VT[2][8192] | Ps[2][9216] | MLs[1024]
    __shared__ __align__(16) unsigned char pool[62976];
    _Float16* Qs  = (_Float16*)(pool);
    _Float16* Ks  = (_Float16*)(pool + 9216)  + g * KBLK * LDST;
    _Float16* VT  = (_Float16*)(pool + 27648) + g * ND * VST;
    _Float16* Ps  = (_Float16*)(pool + 44032) + g * QBLK * LDST;
    float2*   MLs = (float2*)(pool + 62464);
    float*    Osum= (float*)(pool + 9216);     // overlays Ks after last use

    const int ht   = tid & 255;        // within-group thread
    const int srow = ht >> 4;          // 0..15 (K/Q row base)
    const int sd0  = (ht & 15) * 4;    // 0..60
    const int vrow = ht >> 2;          // 0..63 (V key)
    const int vd0  = (ht & 3) * 4;     // 0,4,8,12

    // ---- stage Q (scaled by 1/T = 1/8, exact) — group 0 only ----
    if (g == 0) {
        #pragma unroll
        for (int it = 0; it < 4; ++it) {
            const int r = srow + 16 * it;
            float4 f = *(const float4*)&Qp[(size_t)r * ND + sd0];
            f16x4 h = { (_Float16)(f.x * 0.125f), (_Float16)(f.y * 0.125f),
                        (_Float16)(f.z * 0.125f), (_Float16)(f.w * 0.125f) };
            *(f16x4*)&Qs[r * LDST + sd0] = h;
        }
    }
    __syncthreads();

    const int q = 16 * wi + lc;        // this lane's query row
    const f16x8 qf0 = *(const f16x8*)&Qs[q * LDST + 8 * lg];
    const f16x8 qf1 = *(const f16x8*)&Qs[q * LDST + 8 * lg + 32];

    float m = -3.0e38f, lsum = 0.0f, inv_l = 0.0f;

    auto loadK = [&](float4 (&d)[4], int kt_) {
        #pragma unroll
        for (int it = 0; it < 4; ++it)
            d[it] = *(const float4*)&Kp[(size_t)(kt_ * KBLK + srow + 16 * it) * ND + sd0];
    };
    auto writeK = [&](const float4 (&s)[4]) {
        #pragma unroll
        for (int it = 0; it < 4; ++it) {
            f16x4 h = { (_Float16)s[it].x, (_Float16)s[it].y,
                        (_Float16)s[it].z, (_Float16)s[it].w };
            *(f16x4*)&Ks[(srow + 16 * it) * LDST + sd0] = h;
        }
    };
    auto loadV = [&](float4 (&d)[4], int kt_) {
        #pragma unroll
        for (int it = 0; it < 4; ++it)
            d[it] = *(const float4*)&Vp[(size_t)(kt_ * KBLK + vrow) * ND + vd0 + 16 * it];
    };
    auto writeVT = [&](const float4 (&s)[4]) {   // conflict-free swizzled u16 scatter
        #pragma unroll
        for (int it = 0; it < 4; ++it) {
            const float vals[4] = { s[it].x, s[it].y, s[it].z, s[it].w };
            #pragma unroll
            for (int jj = 0; jj < 4; ++jj) {
                const int d = vd0 + 16 * it + jj;
                VT[d * VST + (((vrow >> 3) ^ ((d >> 1) & 7)) << 3) + (vrow & 7)]
                    = (_Float16)vals[jj];
            }
        }
    };

    auto qkT = [&](f32x4 (&sacc)[4]) {   // S^T tile: rows=keys, cols=q
        #pragma unroll
        for (int mt = 0; mt < 4; ++mt) {
            f32x4 z = {0.f, 0.f, 0.f, 0.f};
            f16x8 a0 = *(const f16x8*)&Ks[(16 * mt + lc) * LDST + 8 * lg];
            f16x8 a1 = *(const f16x8*)&Ks[(16 * mt + lc) * LDST + 8 * lg + 32];
            z = MFMA16(a0, qf0, z);
            z = MFMA16(a1, qf1, z);
            sacc[mt] = z;
        }
    };

    auto stats = [&]() {
        f32x4 sacc[4];
        qkT(sacc);
        float tmax = -3.0e38f;
        #pragma unroll
        for (int mt = 0; mt < 4; ++mt)
            #pragma unroll
            for (int r2 = 0; r2 < 4; ++r2)
                tmax = fmaxf(tmax, sacc[mt][r2]);
        tmax = fmaxf(tmax, __shfl_xor(tmax, 16));
        tmax = fmaxf(tmax, __shfl_xor(tmax, 32));
        const float mnew = fmaxf(m, tmax);
        float tsum = 0.f;
        #pragma unroll
        for (int mt = 0; mt < 4; ++mt)
            #pragma unroll
            for (int r2 = 0; r2 < 4; ++r2)
                tsum += __expf(sacc[mt][r2] - mnew);
        tsum += __shfl_xor(tsum, 16);
        tsum += __shfl_xor(tsum, 32);
        lsum = lsum * __expf(m - mnew) + tsum;
        m = mnew;
    };

    // ================= PASS A: group-partial stats over kt = 2t+g =================
    {
        float4 ka[4];
        loadK(ka, g);
        for (int t = 0; t < HKT; ++t) {
            __syncthreads();
            writeK(ka);
            __syncthreads();
            const int nt = (t + 1 < HKT) ? 2 * (t + 1) + g : g;
            loadK(ka, nt);
            stats();
        }
    }

    // ---- merge stats across groups ----
    if (lg == 0) MLs[g * 64 + q] = make_float2(m, lsum);
    __syncthreads();
    {
        const float2 s0 = MLs[q];
        const float2 s1 = MLs[64 + q];
        const float mf = fmaxf(s0.x, s1.x);
        lsum = s0.y * __expf(s0.x - mf) + s1.y * __expf(s1.x - mf);
        m = mf;
        inv_l = 1.0f / lsum;
    }

    f32x4 acc_o[4];
    #pragma unroll
    for (int mt = 0; mt < 4; ++mt) acc_o[mt] = {0.f, 0.f, 0.f, 0.f};

    auto passB = [&](int kt_) {
        f32x4 sacc[4];
        qkT(sacc);
        #pragma unroll
        for (int mt = 0; mt < 4; ++mt) {
            f32x4 p;
            #pragma unroll
            for (int r2 = 0; r2 < 4; ++r2)
                p[r2] = __expf(sacc[mt][r2] - m) * inv_l;
            *(f32x4*)&Ap[(size_t)q * NS + kt_ * KBLK + 16 * mt + 4 * lg] = p;
            f16x4 ph = { (_Float16)p[0], (_Float16)p[1], (_Float16)p[2], (_Float16)p[3] };
            *(f16x4*)&Ps[q * LDST + 16 * mt + 4 * lg] = ph;
        }
        asm volatile("s_waitcnt lgkmcnt(0)" ::: "memory");
        const f16x8 b0 = *(const f16x8*)&Ps[q * LDST + 8 * lg];
        const f16x8 b1 = *(const f16x8*)&Ps[q * LDST + 8 * lg + 32];
        #pragma unroll
        for (int mt = 0; mt < 4; ++mt) {
            const int d  = 16 * mt + lc;
            const int sw = (d >> 1) & 7;
            f16x8 a0 = *(const f16x8*)&VT[d * VST + ((lg ^ sw) << 3)];
            f16x8 a1 = *(const f16x8*)&VT[d * VST + (((lg + 4) ^ sw) << 3)];
            acc_o[mt] = MFMA16(a0, b0, acc_o[mt]);
            acc_o[mt] = MFMA16(a1, b1, acc_o[mt]);
        }
    };

    // ================= PASS B: attn write + PV over kt = 2t+g =================
    {
        float4 ka[4], va[4];
        loadK(ka, g); loadV(va, g);
        for (int t = 0; t < HKT; ++t) {
            __syncthreads();
            writeK(ka); writeVT(va);
            __syncthreads();
            const int nt = (t + 1 < HKT) ? 2 * (t + 1) + g : g;
            loadK(ka, nt); loadV(va, nt);
            passB(2 * t + g);
        }
    }

    // ---- merge partial O across groups, write out ----
    __syncthreads();
    if (g == 1) {
        #pragma unroll
        for (int mt = 0; mt < 4; ++mt)
            *(f32x4*)&Osum[q * OST + 16 * mt + 4 * lg] = acc_o[mt];
    }
    __syncthreads();
    if (g == 0) {
        #pragma unroll
        for (int mt = 0; mt < 4; ++mt) {
            f32x4 o = acc_o[mt];
            const f32x4 ppart = *(const f32x4*)&Osum[q * OST + 16 * mt + 4 * lg];
            o = o + ppart;
            *(f32x4*)&Op[(size_t)q * ND + 16 * mt + 4 * lg] = o;
        }
    }
}

extern "C" void kernel_launch(void* const* d_in, const int* in_sizes, int n_in,
                              void* d_out, int out_size, void* d_ws, size_t ws_size,
                              hipStream_t stream) {
    const float* q = (const float*)d_in[0];
    const float* k = (const float*)d_in[1];
    const float* v = (const float*)d_in[2];
    float* out  = (float*)d_out;
    float* attn = out + (size_t)NB * NH * NS * ND;  // outputs concatenated: (output, attn)

    dim3 grid(NS / QBLK, NB * NH);
    sdpa_kernel<<<grid, 512, 0, stream>>>(q, k, v, out, attn);
}